// Round 17
// baseline (402.665 us; speedup 1.0000x reference)
//
#include <hip/hip_runtime.h>
#include <hip/hip_fp16.h>

// Affinity propagation: 24 Jacobi iterations of an 8-neighbor weighted stencil.
// OFFSETS (dy,dx): (-1,-1),(-1,0),(-1,1),(0,-1),(0,1),(1,-1),(1,0),(1,1)
// R17 = R16 (tall tiles: 64x144 tile, 40x120 core, 576 threads, NBLK=512,
// XCD swizzle) + __launch_bounds__(576, 1): min-waves/EU=1 maximizes the
// allocator's per-wave VGPR budget. R16 failed ONLY because the allocator
// self-capped at 84 VGPR (persistent state ~110) -> scratch spill (FETCH
// 296MB vs 99MB logical). This is the permissive direction, not R8's clamp.
// LESSONS: __launch_bounds__(256,4) clamps VGPR->64 = spill (R8). 36px/thread
// = 256 VGPR spill (R13). Persistence serializes staging (R14). Runtime
// store bounds regress (R9/R10). Spill signature: VGPR<need + FETCH>>logical.

#define EPSV 1e-6f
#define FUSE   12
#define RING   12
#define CORE_W 40
#define CORE_H 120
#define TILE_W 64
#define SEGS   36                  // strips of 4 rows; tile height 144
#define NTHREADS (16 * SEGS)       // 576 = 9 waves
#define TXN    16                  // 640 / 40
#define TYN    4                   // 480 / 120
#define NBLK   (8 * TXN * TYN)     // 512
#define TPI    (TXN * TYN)         // 64 tiles per image

typedef __attribute__((ext_vector_type(8))) _Float16 half8;
typedef __attribute__((ext_vector_type(4))) _Float16 half4;

__device__ __forceinline__ float dpp_from_left(float v) {
    // lane i gets lane i-1's v (within 16-lane DPP row); qx==0 -> 0.
    int r = __builtin_amdgcn_update_dpp(0, __float_as_int(v), 0x111, 0xF, 0xF, true);
    return __int_as_float(r);
}
__device__ __forceinline__ float dpp_from_right(float v) {
    // lane i gets lane i+1's v; qx==15 -> 0.
    int r = __builtin_amdgcn_update_dpp(0, __float_as_int(v), 0x101, 0xF, 0xF, true);
    return __int_as_float(r);
}

// ---------------------------------------------------------------------------
// Kernel 1: normalize guidance -> fp16 weights (AoS), fp16 bias, fp16 state.
// ---------------------------------------------------------------------------
__global__ __launch_bounds__(256) void precompute_kernel(
    const float* __restrict__ guidance, const float* __restrict__ raw,
    half8* __restrict__ wgt, _Float16* __restrict__ bias,
    _Float16* __restrict__ state, int B, int H, int W)
{
    int idx = blockIdx.x * blockDim.x + threadIdx.x;
    int total = B * H * W;
    if (idx >= total) return;
    int x = idx % W;
    int y = (idx / W) % H;
    int b = idx / (W * H);

    const int dy[8] = {-1,-1,-1, 0, 0, 1, 1, 1};
    const int dx[8] = {-1, 0, 1,-1, 1,-1, 0, 1};

    float g[8];
    float s = 0.f;
#pragma unroll
    for (int c = 0; c < 8; ++c) {
        int yy = y + dy[c], xx = x + dx[c];
        float v = 0.f;
        if (yy >= 0 && yy < H && xx >= 0 && xx < W)
            v = guidance[(((size_t)b * 8 + c) * H + yy) * W + xx];
        g[c] = v;
        s += fabsf(v);
    }
    float inv = 1.f / fmaxf(s, EPSV);
    float wsum = 0.f;
#pragma unroll
    for (int c = 0; c < 8; ++c) { g[c] *= inv; wsum += g[c]; }

    half8 hw;
#pragma unroll
    for (int c = 0; c < 8; ++c) hw[c] = (_Float16)g[c];
    wgt[idx] = hw;

    float r = raw[idx];
    bias[idx]  = (_Float16)((1.f - wsum) * r);
    state[idx] = (_Float16)r;
}

// ---------------------------------------------------------------------------
// Kernel 2: FUSE Jacobi iterations with state in registers.
// Tile = 64x144 px at origin (40*tx-12, 120*ty-12); outside-tile treated as 0
// each iteration (recompute ring): after k iters px at distance >= k from the
// tile edge are exact, so the 40x120 core (distance 12) is exact at k=12.
// Out-of-image px have w=0,b=0,s=0 -> stay 0 (zero-pad exact). Cores tile the
// image disjointly and flush (16x4 grid of 40x120 per image).
// XCD swizzle: t = (bid&7)*TPI + bid>>3 -> XCD k gets image k contiguously.
// ---------------------------------------------------------------------------
template<bool LAST>
__global__ __launch_bounds__(NTHREADS, 1) void prop_fused_kernel(
    const _Float16* __restrict__ src, const half8* __restrict__ wgt,
    const _Float16* __restrict__ bias, _Float16* __restrict__ dst,
    float* __restrict__ dst32)
{
    const int H = 480, W = 640;
    // bufTop[p][s][x]: strip s's row0 (read as "below-row" by strip s-1 at
    // index s; slot SEGS stays 0). bufBot[p][s+1][x]: strip s's row3 (read as
    // "above-row" by strip s+1 at index s+1; slot 0 stays 0).
    __shared__ __align__(16) float bufTop[2][SEGS + 1][TILE_W];
    __shared__ __align__(16) float bufBot[2][SEGS + 1][TILE_W];

    int tid = threadIdx.x;
    int qx  = tid & 15;         // x-quad within tile (DPP row position)
    int seg = tid >> 4;         // 4-row strip within tile, [0, 36)

    int t = (blockIdx.x & 7) * TPI + (blockIdx.x >> 3);   // bijective swizzle
    int tx = t % TXN;
    int tmp = t / TXN;
    int ty = tmp % TYN;
    int b  = tmp / TYN;
    int x0 = tx * CORE_W - RING;
    int y0 = ty * CORE_H - RING;
    size_t plane = (size_t)b * H * W;

    int gx0 = x0 + qx * 4;                       // quad is fully in or out
    bool xok = (gx0 >= 0) & (gx0 + 3 < W);
    int gyb = y0 + seg * 4;

    if (tid < TILE_W) {
        bufBot[0][0][tid]    = 0.f; bufBot[1][0][tid]    = 0.f;
        bufTop[0][SEGS][tid] = 0.f; bufTop[1][SEGS][tid] = 0.f;
    }

    // Per-px weights (half8 = 4 VGPR), bias packed fp16, f32 state (16 px).
    half8 pw[4][4];
    half4 pbq[4];
    float s[4][4];
#pragma unroll
    for (int r = 0; r < 4; ++r) {
        int gy = gyb + r;
        bool ok = xok && gy >= 0 && gy < H;
        if (ok) {
            size_t gb = plane + (size_t)gy * W + gx0;
            const half8* wp = wgt + gb;
            pw[r][0] = wp[0]; pw[r][1] = wp[1]; pw[r][2] = wp[2]; pw[r][3] = wp[3];
            pbq[r] = *(const half4*)(bias + gb);
            half4 sq = *(const half4*)(src + gb);
#pragma unroll
            for (int c = 0; c < 4; ++c) s[r][c] = (float)sq[c];
        } else {
            half8 hz;
#pragma unroll
            for (int c = 0; c < 8; ++c) hz[c] = (_Float16)0.f;
            half4 z4;
#pragma unroll
            for (int c = 0; c < 4; ++c) z4[c] = (_Float16)0.f;
            pbq[r] = z4;
#pragma unroll
            for (int c = 0; c < 4; ++c) { pw[r][c] = hz; s[r][c] = 0.f; }
        }
    }

#pragma unroll 2
    for (int it = 0; it < FUSE; ++it) {
        const int p = it & 1;
        // Exchange strip-boundary rows (old values).
        *(float4*)&bufTop[p][seg][qx * 4]     = make_float4(s[0][0], s[0][1], s[0][2], s[0][3]);
        *(float4*)&bufBot[p][seg + 1][qx * 4] = make_float4(s[3][0], s[3][1], s[3][2], s[3][3]);
        __syncthreads();
        float4 Av = *(const float4*)&bufBot[p][seg][qx * 4];      // row above strip
        float4 Bv = *(const float4*)&bufTop[p][seg + 1][qx * 4];  // row below strip

        // Rolling in-place update (wave-uniform, so DPP of carry regs is safe).
        float u0 = Av.x, u1 = Av.y, u2 = Av.z, u3 = Av.w;
        float ul = dpp_from_left(u3);
        float ur = dpp_from_right(u0);
        float cl = dpp_from_left(s[0][3]);
        float cr = dpp_from_right(s[0][0]);
#pragma unroll
        for (int r = 0; r < 4; ++r) {
            float D0, D1, D2, D3;
            if (r < 3) { D0 = s[r+1][0]; D1 = s[r+1][1]; D2 = s[r+1][2]; D3 = s[r+1][3]; }
            else       { D0 = Bv.x;      D1 = Bv.y;      D2 = Bv.z;      D3 = Bv.w; }
            float dl = dpp_from_left(D3);
            float dr = dpp_from_right(D0);
            float C0 = s[r][0], C1 = s[r][1], C2 = s[r][2], C3 = s[r][3];
            half8 w0 = pw[r][0], w1 = pw[r][1], w2 = pw[r][2], w3 = pw[r][3];
            float n0 = (float)pbq[r][0]
                + (float)w0[0] * ul + (float)w0[1] * u0 + (float)w0[2] * u1
                + (float)w0[3] * cl + (float)w0[4] * C1
                + (float)w0[5] * dl + (float)w0[6] * D0 + (float)w0[7] * D1;
            float n1 = (float)pbq[r][1]
                + (float)w1[0] * u0 + (float)w1[1] * u1 + (float)w1[2] * u2
                + (float)w1[3] * C0 + (float)w1[4] * C2
                + (float)w1[5] * D0 + (float)w1[6] * D1 + (float)w1[7] * D2;
            float n2 = (float)pbq[r][2]
                + (float)w2[0] * u1 + (float)w2[1] * u2 + (float)w2[2] * u3
                + (float)w2[3] * C1 + (float)w2[4] * C3
                + (float)w2[5] * D1 + (float)w2[6] * D2 + (float)w2[7] * D3;
            float n3 = (float)pbq[r][3]
                + (float)w3[0] * u2 + (float)w3[1] * u3 + (float)w3[2] * ur
                + (float)w3[3] * C2 + (float)w3[4] * cr
                + (float)w3[5] * D2 + (float)w3[6] * D3 + (float)w3[7] * dr;
            u0 = C0; u1 = C1; u2 = C2; u3 = C3; ul = cl; ur = cr;
            cl = dl; cr = dr;
            s[r][0] = n0; s[r][1] = n1; s[r][2] = n2; s[r][3] = n3;
        }
    }

    // Store the 40x120 core: quads 3..12, strips 3..32 (static lane pattern);
    // all stored px unconditionally in-image (cores flush in x and y).
    bool core = (qx >= 3) & (qx < 13) & (seg >= 3) & (seg < 33);
    if (core) {
#pragma unroll
        for (int r = 0; r < 4; ++r) {
            int gy = gyb + r;                       // in [0,480) by construction
            size_t gb = plane + (size_t)gy * W + gx0;
            if (LAST) {
                *(float4*)(dst32 + gb) = make_float4(s[r][0], s[r][1], s[r][2], s[r][3]);
            } else {
                half4 hv;
                hv[0] = (_Float16)s[r][0]; hv[1] = (_Float16)s[r][1];
                hv[2] = (_Float16)s[r][2]; hv[3] = (_Float16)s[r][3];
                *(half4*)(dst + gb) = hv;
            }
        }
    }
}

// ---------------------------------------------------------------------------
extern "C" void kernel_launch(void* const* d_in, const int* in_sizes, int n_in,
                              void* d_out, int out_size, void* d_ws, size_t ws_size,
                              hipStream_t stream) {
    const float* guidance = (const float*)d_in[0];
    const float* raw      = (const float*)d_in[1];
    float* out = (float*)d_out;

    const int B = 8, H = 480, W = 640;
    const size_t npix = (size_t)B * H * W;

    // Workspace: wgt half8 (npix*16B) | bias fp16 | p0 fp16 | p1 fp16
    half8*    wgt  = (half8*)d_ws;
    _Float16* bias = (_Float16*)((char*)d_ws + npix * sizeof(half8));
    _Float16* p0   = bias + npix;
    _Float16* p1   = p0 + npix;

    {
        int blocks = (int)((npix + 255) / 256);
        precompute_kernel<<<blocks, 256, 0, stream>>>(guidance, raw, wgt, bias,
                                                      p0, B, H, W);
    }

    // 2 launches x FUSE=12 = 24 iterations. p0 -> p1 -> out(f32).
    prop_fused_kernel<false><<<NBLK, NTHREADS, 0, stream>>>(p0, wgt, bias, p1, nullptr);
    prop_fused_kernel<true ><<<NBLK, NTHREADS, 0, stream>>>(p1, wgt, bias, nullptr, out);
}

// Round 18
// 103.886 us; speedup vs baseline: 3.8760x; 3.8760x over previous
//
#include <hip/hip_runtime.h>
#include <hip/hip_fp16.h>

// Affinity propagation: 24 Jacobi iterations of an 8-neighbor weighted stencil.
// OFFSETS (dy,dx): (-1,-1),(-1,0),(-1,1),(0,-1),(0,1),(1,-1),(1,0),(1,1)
// R18: tall tile with 512-THREAD blocks (8 waves — power of two). Allocator
// heuristic at 8-wave blocks targeting 2 blocks/CU = 128 VGPR budget, which
// fits our ~115-VGPR state (16 px/thread, same as R15). Tile 64x128 (32
// strips), vertical ring 16 / horizontal ring 12, core 40x96 flush (16x5
// grid/image), NBLK=640. Staging 126->105 MB/launch, px-iters -17% vs R15.
// 576-thread blocks self-cap at 84 VGPR -> spill (R16/R17) — 512 is the bet.
// Fallback if spilled (VGPR<100, FETCH>>logical): revert to R15 (94.58us).
// LESSONS: __launch_bounds__(256,4) clamps VGPR->64 = spill (R8). 36px/thread
// = 256 VGPR spill (R13). Persistence serializes staging (R14). Runtime
// store bounds regress (R9/R10).

#define EPSV 1e-6f
#define FUSE   12
#define RINGX  12
#define RINGY  16
#define CORE_W 40
#define CORE_H 96
#define TILE_W 64
#define SEGS   32                  // strips of 4 rows; tile height 128
#define NTHREADS (16 * SEGS)       // 512 = 8 waves
#define TXN    16                  // 640 / 40
#define TYN    5                   // 480 / 96
#define NBLK   (8 * TXN * TYN)     // 640
#define TPI    (TXN * TYN)         // 80 tiles per image

typedef __attribute__((ext_vector_type(8))) _Float16 half8;
typedef __attribute__((ext_vector_type(4))) _Float16 half4;

__device__ __forceinline__ float dpp_from_left(float v) {
    // lane i gets lane i-1's v (within 16-lane DPP row); qx==0 -> 0.
    int r = __builtin_amdgcn_update_dpp(0, __float_as_int(v), 0x111, 0xF, 0xF, true);
    return __int_as_float(r);
}
__device__ __forceinline__ float dpp_from_right(float v) {
    // lane i gets lane i+1's v; qx==15 -> 0.
    int r = __builtin_amdgcn_update_dpp(0, __float_as_int(v), 0x101, 0xF, 0xF, true);
    return __int_as_float(r);
}

// ---------------------------------------------------------------------------
// Kernel 1: normalize guidance -> fp16 weights (AoS), fp16 bias, fp16 state.
// ---------------------------------------------------------------------------
__global__ __launch_bounds__(256) void precompute_kernel(
    const float* __restrict__ guidance, const float* __restrict__ raw,
    half8* __restrict__ wgt, _Float16* __restrict__ bias,
    _Float16* __restrict__ state, int B, int H, int W)
{
    int idx = blockIdx.x * blockDim.x + threadIdx.x;
    int total = B * H * W;
    if (idx >= total) return;
    int x = idx % W;
    int y = (idx / W) % H;
    int b = idx / (W * H);

    const int dy[8] = {-1,-1,-1, 0, 0, 1, 1, 1};
    const int dx[8] = {-1, 0, 1,-1, 1,-1, 0, 1};

    float g[8];
    float s = 0.f;
#pragma unroll
    for (int c = 0; c < 8; ++c) {
        int yy = y + dy[c], xx = x + dx[c];
        float v = 0.f;
        if (yy >= 0 && yy < H && xx >= 0 && xx < W)
            v = guidance[(((size_t)b * 8 + c) * H + yy) * W + xx];
        g[c] = v;
        s += fabsf(v);
    }
    float inv = 1.f / fmaxf(s, EPSV);
    float wsum = 0.f;
#pragma unroll
    for (int c = 0; c < 8; ++c) { g[c] *= inv; wsum += g[c]; }

    half8 hw;
#pragma unroll
    for (int c = 0; c < 8; ++c) hw[c] = (_Float16)g[c];
    wgt[idx] = hw;

    float r = raw[idx];
    bias[idx]  = (_Float16)((1.f - wsum) * r);
    state[idx] = (_Float16)r;
}

// ---------------------------------------------------------------------------
// Kernel 2: FUSE Jacobi iterations with state in registers.
// Tile = 64x128 px at origin (40*tx-12, 96*ty-16); outside-tile treated as 0
// each iteration (recompute ring): after k iters px at distance >= k from the
// tile edge are exact; core is at horizontal distance 12 and vertical
// distance 16, both >= FUSE=12 -> 40x96 core exact. Out-of-image px have
// w=0,b=0,s=0 -> stay 0 (zero-pad exact). Cores tile the image disjointly
// and flush (16x5 grid of 40x96 per image). XCD swizzle: t = (bid&7)*TPI +
// bid>>3 -> XCD k gets image k contiguously (halo re-reads in its own L2).
// ---------------------------------------------------------------------------
template<bool LAST>
__global__ __launch_bounds__(NTHREADS) void prop_fused_kernel(
    const _Float16* __restrict__ src, const half8* __restrict__ wgt,
    const _Float16* __restrict__ bias, _Float16* __restrict__ dst,
    float* __restrict__ dst32)
{
    const int H = 480, W = 640;
    // bufTop[p][s][x]: strip s's row0 (read as "below-row" by strip s-1 at
    // index s; slot SEGS stays 0). bufBot[p][s+1][x]: strip s's row3 (read as
    // "above-row" by strip s+1 at index s+1; slot 0 stays 0).
    __shared__ __align__(16) float bufTop[2][SEGS + 1][TILE_W];
    __shared__ __align__(16) float bufBot[2][SEGS + 1][TILE_W];

    int tid = threadIdx.x;
    int qx  = tid & 15;         // x-quad within tile (DPP row position)
    int seg = tid >> 4;         // 4-row strip within tile, [0, 32)

    int t = (blockIdx.x & 7) * TPI + (blockIdx.x >> 3);   // bijective swizzle
    int tx = t % TXN;
    int tmp = t / TXN;
    int ty = tmp % TYN;
    int b  = tmp / TYN;
    int x0 = tx * CORE_W - RINGX;
    int y0 = ty * CORE_H - RINGY;
    size_t plane = (size_t)b * H * W;

    int gx0 = x0 + qx * 4;                       // quad is fully in or out
    bool xok = (gx0 >= 0) & (gx0 + 3 < W);
    int gyb = y0 + seg * 4;

    if (tid < TILE_W) {
        bufBot[0][0][tid]    = 0.f; bufBot[1][0][tid]    = 0.f;
        bufTop[0][SEGS][tid] = 0.f; bufTop[1][SEGS][tid] = 0.f;
    }

    // Per-px weights (half8 = 4 VGPR), bias packed fp16, f32 state (16 px).
    half8 pw[4][4];
    half4 pbq[4];
    float s[4][4];
#pragma unroll
    for (int r = 0; r < 4; ++r) {
        int gy = gyb + r;
        bool ok = xok && gy >= 0 && gy < H;
        if (ok) {
            size_t gb = plane + (size_t)gy * W + gx0;
            const half8* wp = wgt + gb;
            pw[r][0] = wp[0]; pw[r][1] = wp[1]; pw[r][2] = wp[2]; pw[r][3] = wp[3];
            pbq[r] = *(const half4*)(bias + gb);
            half4 sq = *(const half4*)(src + gb);
#pragma unroll
            for (int c = 0; c < 4; ++c) s[r][c] = (float)sq[c];
        } else {
            half8 hz;
#pragma unroll
            for (int c = 0; c < 8; ++c) hz[c] = (_Float16)0.f;
            half4 z4;
#pragma unroll
            for (int c = 0; c < 4; ++c) z4[c] = (_Float16)0.f;
            pbq[r] = z4;
#pragma unroll
            for (int c = 0; c < 4; ++c) { pw[r][c] = hz; s[r][c] = 0.f; }
        }
    }

#pragma unroll 2
    for (int it = 0; it < FUSE; ++it) {
        const int p = it & 1;
        // Exchange strip-boundary rows (old values).
        *(float4*)&bufTop[p][seg][qx * 4]     = make_float4(s[0][0], s[0][1], s[0][2], s[0][3]);
        *(float4*)&bufBot[p][seg + 1][qx * 4] = make_float4(s[3][0], s[3][1], s[3][2], s[3][3]);
        __syncthreads();
        float4 Av = *(const float4*)&bufBot[p][seg][qx * 4];      // row above strip
        float4 Bv = *(const float4*)&bufTop[p][seg + 1][qx * 4];  // row below strip

        // Rolling in-place update (wave-uniform, so DPP of carry regs is safe).
        float u0 = Av.x, u1 = Av.y, u2 = Av.z, u3 = Av.w;
        float ul = dpp_from_left(u3);
        float ur = dpp_from_right(u0);
        float cl = dpp_from_left(s[0][3]);
        float cr = dpp_from_right(s[0][0]);
#pragma unroll
        for (int r = 0; r < 4; ++r) {
            float D0, D1, D2, D3;
            if (r < 3) { D0 = s[r+1][0]; D1 = s[r+1][1]; D2 = s[r+1][2]; D3 = s[r+1][3]; }
            else       { D0 = Bv.x;      D1 = Bv.y;      D2 = Bv.z;      D3 = Bv.w; }
            float dl = dpp_from_left(D3);
            float dr = dpp_from_right(D0);
            float C0 = s[r][0], C1 = s[r][1], C2 = s[r][2], C3 = s[r][3];
            half8 w0 = pw[r][0], w1 = pw[r][1], w2 = pw[r][2], w3 = pw[r][3];
            float n0 = (float)pbq[r][0]
                + (float)w0[0] * ul + (float)w0[1] * u0 + (float)w0[2] * u1
                + (float)w0[3] * cl + (float)w0[4] * C1
                + (float)w0[5] * dl + (float)w0[6] * D0 + (float)w0[7] * D1;
            float n1 = (float)pbq[r][1]
                + (float)w1[0] * u0 + (float)w1[1] * u1 + (float)w1[2] * u2
                + (float)w1[3] * C0 + (float)w1[4] * C2
                + (float)w1[5] * D0 + (float)w1[6] * D1 + (float)w1[7] * D2;
            float n2 = (float)pbq[r][2]
                + (float)w2[0] * u1 + (float)w2[1] * u2 + (float)w2[2] * u3
                + (float)w2[3] * C1 + (float)w2[4] * C3
                + (float)w2[5] * D1 + (float)w2[6] * D2 + (float)w2[7] * D3;
            float n3 = (float)pbq[r][3]
                + (float)w3[0] * u2 + (float)w3[1] * u3 + (float)w3[2] * ur
                + (float)w3[3] * C2 + (float)w3[4] * cr
                + (float)w3[5] * D2 + (float)w3[6] * D3 + (float)w3[7] * dr;
            u0 = C0; u1 = C1; u2 = C2; u3 = C3; ul = cl; ur = cr;
            cl = dl; cr = dr;
            s[r][0] = n0; s[r][1] = n1; s[r][2] = n2; s[r][3] = n3;
        }
    }

    // Store the 40x96 core: quads 3..12, strips 4..27 (static lane pattern).
    // x: gx = 40*tx + [0,40) in [0,640); y: gy = 96*ty + [0,96) in [0,480) —
    // all stored px unconditionally in-image (cores flush both axes).
    bool core = (qx >= 3) & (qx < 13) & (seg >= 4) & (seg < 28);
    if (core) {
#pragma unroll
        for (int r = 0; r < 4; ++r) {
            int gy = gyb + r;
            size_t gb = plane + (size_t)gy * W + gx0;
            if (LAST) {
                *(float4*)(dst32 + gb) = make_float4(s[r][0], s[r][1], s[r][2], s[r][3]);
            } else {
                half4 hv;
                hv[0] = (_Float16)s[r][0]; hv[1] = (_Float16)s[r][1];
                hv[2] = (_Float16)s[r][2]; hv[3] = (_Float16)s[r][3];
                *(half4*)(dst + gb) = hv;
            }
        }
    }
}

// ---------------------------------------------------------------------------
extern "C" void kernel_launch(void* const* d_in, const int* in_sizes, int n_in,
                              void* d_out, int out_size, void* d_ws, size_t ws_size,
                              hipStream_t stream) {
    const float* guidance = (const float*)d_in[0];
    const float* raw      = (const float*)d_in[1];
    float* out = (float*)d_out;

    const int B = 8, H = 480, W = 640;
    const size_t npix = (size_t)B * H * W;

    // Workspace: wgt half8 (npix*16B) | bias fp16 | p0 fp16 | p1 fp16
    half8*    wgt  = (half8*)d_ws;
    _Float16* bias = (_Float16*)((char*)d_ws + npix * sizeof(half8));
    _Float16* p0   = bias + npix;
    _Float16* p1   = p0 + npix;

    {
        int blocks = (int)((npix + 255) / 256);
        precompute_kernel<<<blocks, 256, 0, stream>>>(guidance, raw, wgt, bias,
                                                      p0, B, H, W);
    }

    // 2 launches x FUSE=12 = 24 iterations. p0 -> p1 -> out(f32).
    prop_fused_kernel<false><<<NBLK, NTHREADS, 0, stream>>>(p0, wgt, bias, p1, nullptr);
    prop_fused_kernel<true ><<<NBLK, NTHREADS, 0, stream>>>(p1, wgt, bias, nullptr, out);
}

// Round 19
// 93.154 us; speedup vs baseline: 4.3226x; 1.1152x over previous
//
#include <hip/hip_runtime.h>
#include <hip/hip_fp16.h>

// Affinity propagation: 24 Jacobi iterations of an 8-neighbor weighted stencil.
// OFFSETS (dy,dx): (-1,-1),(-1,0),(-1,1),(0,-1),(0,1),(1,-1),(1,0),(1,1)
// R19 = R15 (best: 94.58us — FUSE=12 x 2 launches, 64x64 tile, 40x40 flush
// core, 256-thread blocks, register weights, DPP horizontal + LDS vertical
// exchange, XCD-swizzled prop grid, static store predicate) + XCD swizzle on
// the PRECOMPUTE grid too: 9600 = 8*1200 blocks, i' = (i%8)*1200 + i/8 ->
// image k's weights are produced on XCD k, where prop launch 1 consumes them.
// GEOMETRY LESSONS (R13-R18 all lost to R15): 576-thr blocks self-cap 84 VGPR
// -> spill (R16/R17); 512-thr blocks = coarse phases (R18, 103.9); 36px/thr
// = 256 VGPR spill (R13); persistent 2-tile blocks serialize staging (R14);
// __launch_bounds__(256,4) clamps VGPR->64 (R8); runtime store bounds regress
// (R9/R10). 256 threads / 16px/thread / 40x40 core is the stable point.

#define EPSV 1e-6f
#define FUSE   12
#define CORE   40                 // output core per 64x64 tile
#define TXN    16                 // 640 / 40
#define TYN    12                 // 480 / 40
#define NBLK   (8 * TXN * TYN)    // 1536
#define TPI    (TXN * TYN)        // 192 tiles per image = NBLK/8

typedef __attribute__((ext_vector_type(8))) _Float16 half8;
typedef __attribute__((ext_vector_type(4))) _Float16 half4;

__device__ __forceinline__ float dpp_from_left(float v) {
    // lane i gets lane i-1's v (within 16-lane DPP row); qx==0 -> 0.
    int r = __builtin_amdgcn_update_dpp(0, __float_as_int(v), 0x111, 0xF, 0xF, true);
    return __int_as_float(r);
}
__device__ __forceinline__ float dpp_from_right(float v) {
    // lane i gets lane i+1's v; qx==15 -> 0.
    int r = __builtin_amdgcn_update_dpp(0, __float_as_int(v), 0x101, 0xF, 0xF, true);
    return __int_as_float(r);
}

// ---------------------------------------------------------------------------
// Kernel 1: normalize guidance -> fp16 weights (AoS), fp16 bias, fp16 state.
// Grid 9600 = 8 * 1200 blocks; XCD swizzle puts image k's blocks on XCD k
// (same mapping the prop kernel uses), so launch-1 reads hit the same L2.
// ---------------------------------------------------------------------------
#define PRE_BLOCKS 9600
#define PRE_BPI    1200            // blocks per image

__global__ __launch_bounds__(256) void precompute_kernel(
    const float* __restrict__ guidance, const float* __restrict__ raw,
    half8* __restrict__ wgt, _Float16* __restrict__ bias,
    _Float16* __restrict__ state, int B, int H, int W)
{
    // Bijective XCD swizzle: blocks 8k+j -> logical block j*... image-major.
    int lb = (blockIdx.x & 7) * PRE_BPI + (blockIdx.x >> 3);
    int idx = lb * blockDim.x + threadIdx.x;
    int total = B * H * W;
    if (idx >= total) return;
    int x = idx % W;
    int y = (idx / W) % H;
    int b = idx / (W * H);

    const int dy[8] = {-1,-1,-1, 0, 0, 1, 1, 1};
    const int dx[8] = {-1, 0, 1,-1, 1,-1, 0, 1};

    float g[8];
    float s = 0.f;
#pragma unroll
    for (int c = 0; c < 8; ++c) {
        int yy = y + dy[c], xx = x + dx[c];
        float v = 0.f;
        if (yy >= 0 && yy < H && xx >= 0 && xx < W)
            v = guidance[(((size_t)b * 8 + c) * H + yy) * W + xx];
        g[c] = v;
        s += fabsf(v);
    }
    float inv = 1.f / fmaxf(s, EPSV);
    float wsum = 0.f;
#pragma unroll
    for (int c = 0; c < 8; ++c) { g[c] *= inv; wsum += g[c]; }

    half8 hw;
#pragma unroll
    for (int c = 0; c < 8; ++c) hw[c] = (_Float16)g[c];
    wgt[idx] = hw;

    float r = raw[idx];
    bias[idx]  = (_Float16)((1.f - wsum) * r);
    state[idx] = (_Float16)r;
}

// ---------------------------------------------------------------------------
// Kernel 2: FUSE Jacobi iterations with state in registers.
// Tile = 64x64 px at origin (40*tx-12, 40*ty-12); outside-tile treated as 0
// each iteration (recompute ring): after k iters px at distance >= k from the
// tile edge are exact, so the 40x40 core (distance 12) is exact at k=FUSE=12.
// Out-of-image px have w=0,b=0,s=0 -> stay 0, matching zero-pad semantics.
// Cores tile the image disjointly and exactly (16x12 grid of 40x40).
// XCD swizzle: t = (bid&7)*TPI + bid>>3 -> XCD k gets image k contiguously.
// ---------------------------------------------------------------------------
template<bool LAST>
__global__ __launch_bounds__(256) void prop_fused_kernel(
    const _Float16* __restrict__ src, const half8* __restrict__ wgt,
    const _Float16* __restrict__ bias, _Float16* __restrict__ dst,
    float* __restrict__ dst32)
{
    const int H = 480, W = 640;
    // bufTop[p][s][x]: strip s's row0 (read as "below-row" by strip s-1 at
    // index s; slot 16 stays 0). bufBot[p][s+1][x]: strip s's row3 (read as
    // "above-row" by strip s+1 at index s+1; slot 0 stays 0).
    __shared__ __align__(16) float bufTop[2][17][64];
    __shared__ __align__(16) float bufBot[2][17][64];

    int tid = threadIdx.x;
    int qx = tid & 15;          // x-quad within tile (DPP row position)
    int sy = tid >> 4;          // 4-row strip within tile

    // XCD-aware swizzle (bijective; NBLK % 8 == 0).
    int t = (blockIdx.x & 7) * TPI + (blockIdx.x >> 3);
    int tx = t % TXN;
    int tmp = t / TXN;
    int ty = tmp % TYN;
    int b  = tmp / TYN;
    int x0 = tx * CORE - FUSE;
    int y0 = ty * CORE - FUSE;
    size_t plane = (size_t)b * H * W;

    int gx0 = x0 + qx * 4;                       // quad is fully in or out
    bool xok = (gx0 >= 0) & (gx0 + 3 < W);
    int gyb = y0 + sy * 4;

    if (tid < 64) {
        bufBot[0][0][tid]  = 0.f; bufBot[1][0][tid]  = 0.f;
        bufTop[0][16][tid] = 0.f; bufTop[1][16][tid] = 0.f;
    }

    // Per-px weights (half8 = 4 VGPR), bias packed fp16, f32 state.
    half8 pw[4][4];
    half4 pbq[4];
    float s[4][4];
#pragma unroll
    for (int r = 0; r < 4; ++r) {
        int gy = gyb + r;
        bool ok = xok && gy >= 0 && gy < H;
        if (ok) {
            size_t gb = plane + (size_t)gy * W + gx0;
            const half8* wp = wgt + gb;
            pw[r][0] = wp[0]; pw[r][1] = wp[1]; pw[r][2] = wp[2]; pw[r][3] = wp[3];
            pbq[r] = *(const half4*)(bias + gb);
            half4 sq = *(const half4*)(src + gb);
#pragma unroll
            for (int c = 0; c < 4; ++c) s[r][c] = (float)sq[c];
        } else {
            half8 hz;
#pragma unroll
            for (int c = 0; c < 8; ++c) hz[c] = (_Float16)0.f;
            half4 z4;
#pragma unroll
            for (int c = 0; c < 4; ++c) z4[c] = (_Float16)0.f;
            pbq[r] = z4;
#pragma unroll
            for (int c = 0; c < 4; ++c) { pw[r][c] = hz; s[r][c] = 0.f; }
        }
    }

#pragma unroll 2
    for (int it = 0; it < FUSE; ++it) {
        const int p = it & 1;
        // Exchange strip-boundary rows (old values).
        *(float4*)&bufTop[p][sy][qx * 4]     = make_float4(s[0][0], s[0][1], s[0][2], s[0][3]);
        *(float4*)&bufBot[p][sy + 1][qx * 4] = make_float4(s[3][0], s[3][1], s[3][2], s[3][3]);
        __syncthreads();
        float4 Av = *(const float4*)&bufBot[p][sy][qx * 4];      // row above strip
        float4 Bv = *(const float4*)&bufTop[p][sy + 1][qx * 4];  // row below strip

        // Rolling in-place update (wave-uniform, so DPP of carry regs is safe).
        float u0 = Av.x, u1 = Av.y, u2 = Av.z, u3 = Av.w;
        float ul = dpp_from_left(u3);
        float ur = dpp_from_right(u0);
        float cl = dpp_from_left(s[0][3]);
        float cr = dpp_from_right(s[0][0]);
#pragma unroll
        for (int r = 0; r < 4; ++r) {
            float D0, D1, D2, D3;
            if (r < 3) { D0 = s[r+1][0]; D1 = s[r+1][1]; D2 = s[r+1][2]; D3 = s[r+1][3]; }
            else       { D0 = Bv.x;      D1 = Bv.y;      D2 = Bv.z;      D3 = Bv.w; }
            float dl = dpp_from_left(D3);
            float dr = dpp_from_right(D0);
            float C0 = s[r][0], C1 = s[r][1], C2 = s[r][2], C3 = s[r][3];
            half8 w0 = pw[r][0], w1 = pw[r][1], w2 = pw[r][2], w3 = pw[r][3];
            float n0 = (float)pbq[r][0]
                + (float)w0[0] * ul + (float)w0[1] * u0 + (float)w0[2] * u1
                + (float)w0[3] * cl + (float)w0[4] * C1
                + (float)w0[5] * dl + (float)w0[6] * D0 + (float)w0[7] * D1;
            float n1 = (float)pbq[r][1]
                + (float)w1[0] * u0 + (float)w1[1] * u1 + (float)w1[2] * u2
                + (float)w1[3] * C0 + (float)w1[4] * C2
                + (float)w1[5] * D0 + (float)w1[6] * D1 + (float)w1[7] * D2;
            float n2 = (float)pbq[r][2]
                + (float)w2[0] * u1 + (float)w2[1] * u2 + (float)w2[2] * u3
                + (float)w2[3] * C1 + (float)w2[4] * C3
                + (float)w2[5] * D1 + (float)w2[6] * D2 + (float)w2[7] * D3;
            float n3 = (float)pbq[r][3]
                + (float)w3[0] * u2 + (float)w3[1] * u3 + (float)w3[2] * ur
                + (float)w3[3] * C2 + (float)w3[4] * cr
                + (float)w3[5] * D2 + (float)w3[6] * D3 + (float)w3[7] * dr;
            u0 = C0; u1 = C1; u2 = C2; u3 = C3; ul = cl; ur = cr;
            cl = dl; cr = dr;
            s[r][0] = n0; s[r][1] = n1; s[r][2] = n2; s[r][3] = n3;
        }
    }

    // Store the 40x40 core: quads/strips 3..12 inclusive. Static lane-pattern
    // predicate; all stored px are unconditionally in-image (cores flush).
    bool core = (qx >= 3) & (qx < 13) & (sy >= 3) & (sy < 13);
    if (core) {
#pragma unroll
        for (int r = 0; r < 4; ++r) {
            int gy = gyb + r;                       // in [0,480) by construction
            size_t gb = plane + (size_t)gy * W + gx0;
            if (LAST) {
                *(float4*)(dst32 + gb) = make_float4(s[r][0], s[r][1], s[r][2], s[r][3]);
            } else {
                half4 hv;
                hv[0] = (_Float16)s[r][0]; hv[1] = (_Float16)s[r][1];
                hv[2] = (_Float16)s[r][2]; hv[3] = (_Float16)s[r][3];
                *(half4*)(dst + gb) = hv;
            }
        }
    }
}

// ---------------------------------------------------------------------------
extern "C" void kernel_launch(void* const* d_in, const int* in_sizes, int n_in,
                              void* d_out, int out_size, void* d_ws, size_t ws_size,
                              hipStream_t stream) {
    const float* guidance = (const float*)d_in[0];
    const float* raw      = (const float*)d_in[1];
    float* out = (float*)d_out;

    const int B = 8, H = 480, W = 640;
    const size_t npix = (size_t)B * H * W;

    // Workspace: wgt half8 (npix*16B) | bias fp16 | p0 fp16 | p1 fp16
    half8*    wgt  = (half8*)d_ws;
    _Float16* bias = (_Float16*)((char*)d_ws + npix * sizeof(half8));
    _Float16* p0   = bias + npix;
    _Float16* p1   = p0 + npix;

    precompute_kernel<<<PRE_BLOCKS, 256, 0, stream>>>(guidance, raw, wgt, bias,
                                                      p0, B, H, W);

    // 2 launches x FUSE=12 = 24 iterations. p0 -> p1 -> out(f32).
    prop_fused_kernel<false><<<NBLK, 256, 0, stream>>>(p0, wgt, bias, p1, nullptr);
    prop_fused_kernel<true ><<<NBLK, 256, 0, stream>>>(p1, wgt, bias, nullptr, out);
}